// Round 3
// baseline (93.164 us; speedup 1.0000x reference)
//
#include <hip/hip_runtime.h>

#define NBINS  10
#define NCLS   80
#define NSLOTS (NCLS * NBINS)   // 800
#define QSCALE 262144.0f        // 2^18 fixed-point scale for sum(p)

// ---------------------------------------------------------------------------
// Kernel 1: per-(class,bin) accumulation. One packed u64 LDS atomic per
// element: bits 0..39 = quantized sum_p, 40..51 = count, 52..63 = correct.
// Slot 800 is a trash slot for out-of-range (p==0) elements.
// ---------------------------------------------------------------------------
__global__ void __launch_bounds__(256)
mce_accum(const float4* __restrict__ probas,
          const int*    __restrict__ labels,
          unsigned long long* __restrict__ g_cntacc,  // low32=cnt, high32=acc
          unsigned long long* __restrict__ g_sum,     // quantized sum_p
          unsigned int nvec) {
    __shared__ unsigned long long s_pack[NSLOTS + 1];

    for (int i = threadIdx.x; i < NSLOTS + 1; i += 256) s_pack[i] = 0ull;
    __syncthreads();

    const unsigned int stride = gridDim.x * 256u * 4u;   // float4 units

    for (unsigned int v = (blockIdx.x * 256u + threadIdx.x) * 4u;
         v < nvec; v += stride) {
        float4 q0 = probas[v];
        float4 q1 = probas[v + 1];
        float4 q2 = probas[v + 2];
        float4 q3 = probas[v + 3];
        unsigned int row = v / 20u;                 // 32-bit magic div
        int cbase  = (int)(v - row * 20u) * 4;      // first class of this group
        int labrel = labels[row] - cbase;           // relative label index
        int base10 = cbase * NBINS;

        float pv[16] = {q0.x, q0.y, q0.z, q0.w,
                        q1.x, q1.y, q1.z, q1.w,
                        q2.x, q2.y, q2.z, q2.w,
                        q3.x, q3.y, q3.z, q3.w};
        #pragma unroll
        for (int j = 0; j < 16; ++j) {
            float p = pv[j];
            // bin = (#edges < p) - 1, edges e[k] ~ k*0.1f; p==0 -> -1 (trash)
            int b = (int)(p * 10.0f);
            if (b > 9) b = 9;
            float eb = (float)b * 0.1f;
            if (!(eb < p)) {
                b -= 1;
            } else {
                float eb1 = (float)(b + 1) * 0.1f;
                if (eb1 < p) b += 1;
            }
            int slot = (b >= 0) ? (base10 + j * NBINS + b) : NSLOTS;
            unsigned long long inc =
                (unsigned long long)(unsigned int)(p * QSCALE + 0.5f)
              | (1ull << 40)
              | ((j == labrel) ? (1ull << 52) : 0ull);
            atomicAdd(&s_pack[slot], inc);   // native ds_add_u64
        }
    }
    __syncthreads();

    for (int i = threadIdx.x; i < NSLOTS; i += 256) {
        unsigned long long v = s_pack[i];
        if (v) {
            unsigned long long cnt = (v >> 40) & 0xFFFull;
            unsigned long long acc = (v >> 52);
            unsigned long long q   = v & 0xFFFFFFFFFFull;
            atomicAdd(&g_cntacc[i], cnt | (acc << 32));
            atomicAdd(&g_sum[i], q);
        }
    }
}

// ---------------------------------------------------------------------------
// Kernel 2: finalize in double precision. One block, 128 threads (80 active).
// ---------------------------------------------------------------------------
__global__ void __launch_bounds__(128)
mce_finalize(const unsigned long long* __restrict__ g_cntacc,
             const unsigned long long* __restrict__ g_sum,
             float* __restrict__ out) {
    __shared__ double s_ce[128];
    int c = threadIdx.x;
    double ce = 0.0;
    if (c < NCLS) {
        double total = 0.0;
        for (int b = 0; b < NBINS; ++b)
            total += (double)(unsigned int)(g_cntacc[c * NBINS + b] & 0xFFFFFFFFull);
        for (int b = 0; b < NBINS; ++b) {
            unsigned long long ca = g_cntacc[c * NBINS + b];
            unsigned int n = (unsigned int)(ca & 0xFFFFFFFFull);
            if (n > 0u) {
                double fn   = (double)n;
                double conf = ((double)g_sum[c * NBINS + b] * (1.0 / 262144.0)) / fn;
                double acc  = (double)(unsigned int)(ca >> 32) / fn;
                double d    = conf - acc;
                ce += (fn / total) * d * d;
            }
        }
    }
    s_ce[c] = ce;
    __syncthreads();
    for (int off = 64; off > 0; off >>= 1) {
        if (c < off) s_ce[c] += s_ce[c + off];
        __syncthreads();
    }
    if (c == 0) out[0] = (float)sqrt(s_ce[0] / (double)NCLS);
}

extern "C" void kernel_launch(void* const* d_in, const int* in_sizes, int n_in,
                              void* d_out, int out_size, void* d_ws, size_t ws_size,
                              hipStream_t stream) {
    const float4* probas = (const float4*)d_in[0];
    const int*    labels = (const int*)d_in[1];

    unsigned int nvec = (unsigned int)(in_sizes[0] / 4);  // 20,000,000

    unsigned long long* g_cntacc = (unsigned long long*)d_ws;
    unsigned long long* g_sum    = (unsigned long long*)((char*)d_ws + NSLOTS * 8);

    hipMemsetAsync(d_ws, 0, NSLOTS * 16, stream);

    const int threads = 256;
    const int blocks  = 2048;   // 8 blocks/CU, grid-stride, 4 float4/thread/iter
    mce_accum<<<blocks, threads, 0, stream>>>(probas, labels, g_cntacc, g_sum, nvec);
    mce_finalize<<<1, 128, 0, stream>>>(g_cntacc, g_sum, (float*)d_out);
}